// Round 1
// baseline (10098.273 us; speedup 1.0000x reference)
//
#include <hip/hip_runtime.h>

// Autoregressive LSTM on MI355X.
// B=256, T=256, D=256, H=1024, O=256.
// Strategy: persistent 256-block kernel, fp16 MFMA GEMMs, grid barrier per phase.

typedef _Float16 f16x8 __attribute__((ext_vector_type(8)));
typedef float f32x4 __attribute__((ext_vector_type(4)));

#define BATCH 256
#define TSTEPS 256
#define DIN 256
#define HID 1024
#define OUTD 256
#define KF 1536           // D + H + O
#define NBLK 256

// workspace layout (bytes)
#define WFULLT_OFF 0ull                      // fp16 [4096][1536]  = 12,582,912
#define WDT_OFF    12582912ull               // fp16 [256][1024]   = 524,288
#define XH_OFF     13107200ull               // fp16 [256][256][256] = 33,554,432
#define A0_OFF     46661632ull               // fp16 [256][1536]   = 786,432
#define A1_OFF     47448064ull               // fp16 [256][1536]   = 786,432
#define CST_OFF    48234496ull               // f32  [256][1024]   = 1,048,576
#define BAR_OFF    49283072ull               // int counters
#define WS_NEEDED  49283328ull

__device__ __forceinline__ void gl_lds16(const void* g, void* l) {
    __builtin_amdgcn_global_load_lds(
        (const __attribute__((address_space(1))) unsigned int*)g,
        (__attribute__((address_space(3))) unsigned int*)l, 16, 0, 0);
}

__device__ __forceinline__ float sigf(float x) {
    return 1.0f / (1.0f + __expf(-x));
}
__device__ __forceinline__ float tanhfast(float x) {
    // 1 - 2/(e^{2x}+1); exact at +-inf, ~2ulp elsewhere (fp16 path dominates error)
    return 1.0f - 2.0f / (__expf(2.0f * x) + 1.0f);
}

// monotonic grid barrier: device-scope atomic counter, never reset within a call
__device__ __forceinline__ void gbar(int* cnt, int target) {
    __syncthreads();
    if (threadIdx.x == 0) {
        __hip_atomic_fetch_add(cnt, 1, __ATOMIC_RELEASE, __HIP_MEMORY_SCOPE_AGENT);
        while (__hip_atomic_load(cnt, __ATOMIC_ACQUIRE, __HIP_MEMORY_SCOPE_AGENT) < target) {
            __builtin_amdgcn_s_sleep(4);
        }
    }
    __syncthreads();
}

// ---------------- prep kernels ----------------

// WfullT[n][k] (n z-col 0..4095, k 0..1535): k<256 -> Wx[k][n] (x part);
// 256<=k<1280 -> Wh[k-256][n]; else -> Wx[k-1024][n] (y part).
// WdT[o][k] = Wd[k][o].
__global__ void prep_w(const float* __restrict__ Wx, const float* __restrict__ Wh,
                       const float* __restrict__ Wd,
                       _Float16* __restrict__ WfullT, _Float16* __restrict__ WdT) {
    int bid = blockIdx.x;
    if (bid < 4096) {
        int n = bid;
        for (int k = threadIdx.x; k < KF; k += 256) {
            float v;
            if (k < 256)       v = Wx[(size_t)k * 4096 + n];
            else if (k < 1280) v = Wh[(size_t)(k - 256) * 4096 + n];
            else               v = Wx[(size_t)(k - 1024) * 4096 + n];
            WfullT[(size_t)n * KF + k] = (_Float16)v;
        }
    } else {
        int o = bid - 4096;
        for (int k = threadIdx.x; k < HID; k += 256) {
            WdT[(size_t)o * HID + k] = (_Float16)Wd[(size_t)k * OUTD + o];
        }
    }
}

// convert x to fp16; zero barrier counter
__global__ void prep_x(const float* __restrict__ x, _Float16* __restrict__ xh, int* bar) {
    size_t i0 = ((size_t)blockIdx.x * 256 + threadIdx.x) * 8;
    float4 a = *(const float4*)(x + i0);
    float4 c = *(const float4*)(x + i0 + 4);
    f16x8 v;
    v[0] = (_Float16)a.x; v[1] = (_Float16)a.y; v[2] = (_Float16)a.z; v[3] = (_Float16)a.w;
    v[4] = (_Float16)c.x; v[5] = (_Float16)c.y; v[6] = (_Float16)c.z; v[7] = (_Float16)c.w;
    *(f16x8*)(xh + i0) = v;
    if (blockIdx.x == 0 && threadIdx.x == 0) bar[0] = 0;
}

// ---------------- persistent LSTM kernel ----------------
// grid = 256 blocks x 256 threads (1 block/CU -> co-resident).
// Phase A block mapping: bat0 = (bid>>6)*64, n0 = (bid&63)*16 (hidden tile).
// Phase B block mapping: r0 = (bid>>4)*16 (batch), c0 = (bid&15)*16 (out col).

// stage A chunk [64 rows][128 k] fp16 into LDS with 16B-block XOR swizzle.
// LDS 16B-unit L: row=L>>4, blkS=L&15 stores global blk (blkS ^ (row&15)).
__device__ __forceinline__ void stageA(const _Float16* Acur, _Float16* Al,
                                       int bat0, int k0, int tid) {
#pragma unroll
    for (int r = 0; r < 4; ++r) {
        int L = r * 256 + tid;
        int row = L >> 4;
        int blkG = (L & 15) ^ (row & 15);
        const char* g = (const char*)Acur + ((size_t)(bat0 + row) * KF + k0) * 2 + blkG * 16;
        char* l = (char*)Al + (size_t)(r * 256 + (tid & 192)) * 16;
        gl_lds16(g, l);
    }
}

// stage B: 4 gate strips [16 cols][128 k] each, same swizzle
__device__ __forceinline__ void stageB(const _Float16* WfullT, _Float16* Bl,
                                       int n0, int k0, int tid) {
#pragma unroll
    for (int r = 0; r < 4; ++r) {     // r = gate
        int row = tid >> 4;           // 0..15 (strip col)
        int blkG = (tid & 15) ^ row;
        const char* g = (const char*)WfullT +
            ((size_t)(r * HID + n0 + row) * KF + k0) * 2 + blkG * 16;
        char* l = (char*)Bl + (size_t)(r * 256 + (tid & 192)) * 16;
        gl_lds16(g, l);
    }
}

__device__ __forceinline__ void computeChunk(const _Float16* Al, const _Float16* Bl,
                                             int w, int lane, f32x4 acc[4]) {
    int rl = lane & 15, kg = lane >> 4;
    int aBase = (w * 16 + rl) * 16;
#pragma unroll
    for (int kk8 = 0; kk8 < 16; kk8 += 4) {   // 4 K=32 substeps per 128-chunk
        int s = (kk8 + kg) ^ rl;
        f16x8 av = *(const f16x8*)(Al + (size_t)(aBase + s) * 8);
        f16x8 b0 = *(const f16x8*)(Bl + (size_t)(rl * 16 + s) * 8);
        f16x8 b1 = *(const f16x8*)(Bl + (size_t)(256 + rl * 16 + s) * 8);
        f16x8 b2 = *(const f16x8*)(Bl + (size_t)(512 + rl * 16 + s) * 8);
        f16x8 b3 = *(const f16x8*)(Bl + (size_t)(768 + rl * 16 + s) * 8);
        acc[0] = __builtin_amdgcn_mfma_f32_16x16x32_f16(av, b0, acc[0], 0, 0, 0);
        acc[1] = __builtin_amdgcn_mfma_f32_16x16x32_f16(av, b1, acc[1], 0, 0, 0);
        acc[2] = __builtin_amdgcn_mfma_f32_16x16x32_f16(av, b2, acc[2], 0, 0, 0);
        acc[3] = __builtin_amdgcn_mfma_f32_16x16x32_f16(av, b3, acc[3], 0, 0, 0);
    }
}

__global__ __launch_bounds__(256, 1) void lstm_persist(
        const _Float16* __restrict__ WfullT, const _Float16* __restrict__ WdT,
        const _Float16* __restrict__ xh, const float* __restrict__ b,
        const float* __restrict__ bd,
        _Float16* __restrict__ A0, _Float16* __restrict__ A1,
        float* __restrict__ cst, int* bar, float* __restrict__ out) {
    __shared__ __align__(16) _Float16 AldsBuf[2][64 * 128];
    __shared__ __align__(16) _Float16 BldsBuf[2][4 * 16 * 128];
    __shared__ float red[1024];

    int tid = threadIdx.x, bid = blockIdx.x;
    int w = tid >> 6, lane = tid & 63;
    int rl = lane & 15, kg = lane >> 4;

    // ---- init: A0 = [x_0 | 0 | 0], c = 0 (block bid owns batch row bid) ----
    {
        if (tid < 32) {
            uint4* dst = (uint4*)(A0 + (size_t)bid * KF);
            const uint4* src = (const uint4*)(xh + (size_t)bid * 65536);
            dst[tid] = src[tid];
        }
        uint4 z4; z4.x = z4.y = z4.z = z4.w = 0u;
        if (tid < 160) ((uint4*)(A0 + (size_t)bid * KF + 256))[tid] = z4;
        float4 zf; zf.x = zf.y = zf.z = zf.w = 0.f;
        ((float4*)(cst + (size_t)bid * HID))[tid] = zf;
    }
    int barTarget = NBLK;
    gbar(bar, barTarget);

    const _Float16* Acur = A0;
    _Float16* Anext = A1;
    int bat0 = (bid >> 6) << 6;
    int n0 = (bid & 63) << 4;
    int r0 = (bid >> 4) << 4;
    int c0 = (bid & 15) << 4;

    // epilogue constants (phase A)
    float bi_ = b[n0 + rl];
    float bf_ = b[HID + n0 + rl];
    float bg_ = b[2 * HID + n0 + rl];
    float bo_ = b[3 * HID + n0 + rl];
    float bdv = bd[c0 + (tid & 15)];

    for (int t = 0; t < TSTEPS; ++t) {
        // ======== Phase A: z = A@Wfull + b -> gates -> c,h ========
        f32x4 acc[4];
#pragma unroll
        for (int g = 0; g < 4; ++g) { acc[g][0] = 0.f; acc[g][1] = 0.f; acc[g][2] = 0.f; acc[g][3] = 0.f; }

        stageA(Acur, AldsBuf[0], bat0, 0, tid);
        stageB(WfullT, BldsBuf[0], n0, 0, tid);
        __syncthreads();
        for (int ch = 0; ch < 12; ++ch) {
            int cur = ch & 1;
            if (ch < 11) {
                stageA(Acur, AldsBuf[cur ^ 1], bat0, (ch + 1) * 128, tid);
                stageB(WfullT, BldsBuf[cur ^ 1], n0, (ch + 1) * 128, tid);
            }
            computeChunk(AldsBuf[cur], BldsBuf[cur], w, lane, acc);
            __syncthreads();
        }

        // epilogue: gates, c/h update; write h (fp16) into Anext h-section
        {
            int col = n0 + rl;
            int rbase = bat0 + w * 16 + kg * 4;
#pragma unroll
            for (int r = 0; r < 4; ++r) {
                int row = rbase + r;
                float iv = sigf(acc[0][r] + bi_);
                float fv = sigf(acc[1][r] + bf_);
                float gv = tanhfast(acc[2][r] + bg_);
                float ov = sigf(acc[3][r] + bo_);
                size_t ci = (size_t)row * HID + col;
                float cold = cst[ci];
                float cnew = fv * cold + iv * gv;
                cst[ci] = cnew;
                float h = ov * tanhfast(cnew);
                Anext[(size_t)row * KF + 256 + col] = (_Float16)h;
            }
        }

        barTarget += NBLK;
        gbar(bar, barTarget);

        // ======== Phase B: y = tanh(h@Wd + bd); feed back ========
        {
            f32x4 accB; accB[0] = 0.f; accB[1] = 0.f; accB[2] = 0.f; accB[3] = 0.f;
            const _Float16* hbase = Anext + 256;   // h section
#pragma unroll
            for (int it = 0; it < 8; ++it) {
                int k = (w << 8) + it * 32 + kg * 8;
                f16x8 af = *(const f16x8*)(hbase + (size_t)(r0 + rl) * KF + k);
                f16x8 bf8 = *(const f16x8*)(WdT + (size_t)(c0 + rl) * HID + k);
                accB = __builtin_amdgcn_mfma_f32_16x16x32_f16(af, bf8, accB, 0, 0, 0);
            }
#pragma unroll
            for (int r = 0; r < 4; ++r) red[w * 256 + (kg * 4 + r) * 16 + rl] = accB[r];
            __syncthreads();
            int rr = tid >> 4, cc = tid & 15;
            float s = red[rr * 16 + cc] + red[256 + rr * 16 + cc] +
                      red[512 + rr * 16 + cc] + red[768 + rr * 16 + cc];
            float y = tanhfast(s + bdv);
            out[(size_t)(r0 + rr) * 65536 + (size_t)t * 256 + (c0 + cc)] = y;
            Anext[(size_t)(r0 + rr) * KF + 1280 + (c0 + cc)] = (_Float16)y;
            // stage x_{t+1} into Anext x-section (block bid owns batch row bid)
            if (t < TSTEPS - 1 && tid < 32) {
                const uint4* src = (const uint4*)(xh + (size_t)bid * 65536 + (size_t)(t + 1) * 256);
                uint4* dst = (uint4*)(Anext + (size_t)bid * KF);
                dst[tid] = src[tid];
            }
        }

        if (t < TSTEPS - 1) {
            barTarget += NBLK;
            gbar(bar, barTarget);
        }
        const _Float16* tmp = Acur; Acur = Anext; Anext = (_Float16*)tmp;
    }
}

extern "C" void kernel_launch(void* const* d_in, const int* in_sizes, int n_in,
                              void* d_out, int out_size, void* d_ws, size_t ws_size,
                              hipStream_t stream) {
    const float* x  = (const float*)d_in[0];
    const float* Wx = (const float*)d_in[1];
    const float* Wh = (const float*)d_in[2];
    const float* b  = (const float*)d_in[3];
    const float* Wd = (const float*)d_in[4];
    const float* bd = (const float*)d_in[5];
    float* out = (float*)d_out;
    char* ws = (char*)d_ws;
    if (ws_size < WS_NEEDED) return;   // would corrupt memory otherwise; fail visibly

    _Float16* WfullT = (_Float16*)(ws + WFULLT_OFF);
    _Float16* WdT    = (_Float16*)(ws + WDT_OFF);
    _Float16* xh     = (_Float16*)(ws + XH_OFF);
    _Float16* A0     = (_Float16*)(ws + A0_OFF);
    _Float16* A1     = (_Float16*)(ws + A1_OFF);
    float*    cst    = (float*)(ws + CST_OFF);
    int*      bar    = (int*)(ws + BAR_OFF);

    prep_w<<<4352, 256, 0, stream>>>(Wx, Wh, Wd, WfullT, WdT);
    prep_x<<<8192, 256, 0, stream>>>(x, xh, bar);
    lstm_persist<<<NBLK, 256, 0, stream>>>(WfullT, WdT, xh, b, bd, A0, A1, cst, bar, out);
}